// Round 1
// baseline (63.816 us; speedup 1.0000x reference)
//
#include <hip/hip_runtime.h>
#include <hip/hip_bf16.h>
#include <hip/hip_fp16.h>

// RNNT Joint: logits[b,t,u,c] = relu(f[b,t,:] + g[b,u,:]) . out_w[c,:] + out_b[c]
// f = enc_out @ enc_w^T + enc_b   [8,512,320]
// g = pred_out @ pred_w^T + pred_b [8,128,320]
// Sizes: B=8 T=512 U=128 E=768 P=320 H=320 C=34

typedef _Float16 f16x8 __attribute__((ext_vector_type(8)));
typedef float    f32x4 __attribute__((ext_vector_type(4)));
typedef int      i32x4 __attribute__((ext_vector_type(4)));

#define B_ 8
#define T_ 512
#define U_ 128
#define H_ 320
#define C_ 34

// ---------------------------------------------------------------------------
// Prep: out_w fp32 [34][320] -> fp16 padded [48][320] (rows 34..47 zero)
// ---------------------------------------------------------------------------
__global__ void prep_owb(const float* __restrict__ ow, _Float16* __restrict__ owb) {
    int i = blockIdx.x * 256 + threadIdx.x;  // 48*320 = 15360 = 60*256
    int n = i / H_;
    int k = i - n * H_;
    float v = (n < C_) ? ow[n * H_ + k] : 0.f;
    owb[i] = (_Float16)v;
}

// ---------------------------------------------------------------------------
// Projection GEMM: Out[M][320] = A[M][K] * W[320][K]^T + bias, fp16 out.
// Tile 64x64, K-step 32, 4 waves (2x2 of 32x32), mfma_f32_16x16x32_f16.
// ---------------------------------------------------------------------------
__global__ __launch_bounds__(256, 2)
void proj_kernel(const float* __restrict__ A, const float* __restrict__ W,
                 const float* __restrict__ bias, _Float16* __restrict__ Out,
                 int K) {
    __shared__ _Float16 As[64 * 40];  // pad 32->40: balanced LDS bank classes
    __shared__ _Float16 Ws[64 * 40];

    const int tid = threadIdx.x;
    const int l   = tid & 63;
    const int w   = tid >> 6;
    const int bm  = blockIdx.x * 64;
    const int bn  = blockIdx.y * 64;
    const int wm  = (w >> 1) * 32;
    const int wn  = (w & 1) * 32;
    const int q   = l >> 4;      // 0..3 (k-slice group)
    const int r16 = l & 15;

    const int srow = tid >> 2;        // 0..63
    const int scol = (tid & 3) * 8;   // 0,8,16,24

    f32x4 acc[2][2] = {};

    const float* arow = A + (size_t)(bm + srow) * K + scol;
    const float* wrow = W + (size_t)(bn + srow) * K + scol;

    for (int k0 = 0; k0 < K; k0 += 32) {
        f32x4 a0 = *(const f32x4*)(arow + k0);
        f32x4 a1 = *(const f32x4*)(arow + k0 + 4);
        f32x4 w0 = *(const f32x4*)(wrow + k0);
        f32x4 w1 = *(const f32x4*)(wrow + k0 + 4);

        __syncthreads();  // previous iteration's reads complete

        f16x8 av, wv;
#pragma unroll
        for (int j = 0; j < 4; ++j) {
            av[j]     = (_Float16)a0[j];
            av[4 + j] = (_Float16)a1[j];
            wv[j]     = (_Float16)w0[j];
            wv[4 + j] = (_Float16)w1[j];
        }
        *(f16x8*)&As[srow * 40 + scol] = av;
        *(f16x8*)&Ws[srow * 40 + scol] = wv;

        __syncthreads();

        f16x8 afr0 = *(const f16x8*)&As[(wm + r16) * 40 + q * 8];
        f16x8 afr1 = *(const f16x8*)&As[(wm + 16 + r16) * 40 + q * 8];
        f16x8 bfr0 = *(const f16x8*)&Ws[(wn + r16) * 40 + q * 8];
        f16x8 bfr1 = *(const f16x8*)&Ws[(wn + 16 + r16) * 40 + q * 8];

        acc[0][0] = __builtin_amdgcn_mfma_f32_16x16x32_f16(afr0, bfr0, acc[0][0], 0, 0, 0);
        acc[0][1] = __builtin_amdgcn_mfma_f32_16x16x32_f16(afr0, bfr1, acc[0][1], 0, 0, 0);
        acc[1][0] = __builtin_amdgcn_mfma_f32_16x16x32_f16(afr1, bfr0, acc[1][0], 0, 0, 0);
        acc[1][1] = __builtin_amdgcn_mfma_f32_16x16x32_f16(afr1, bfr1, acc[1][1], 0, 0, 0);
    }

    // Epilogue: C/D layout col = l&15, row = (l>>4)*4 + rr  [m89]
#pragma unroll
    for (int mrep = 0; mrep < 2; ++mrep) {
#pragma unroll
        for (int nrep = 0; nrep < 2; ++nrep) {
            int col  = bn + wn + nrep * 16 + r16;
            float bv = bias[col];
#pragma unroll
            for (int rr = 0; rr < 4; ++rr) {
                int row = bm + wm + mrep * 16 + q * 4 + rr;
                Out[(size_t)row * H_ + col] = (_Float16)(acc[mrep][nrep][rr] + bv);
            }
        }
    }
}

// ---------------------------------------------------------------------------
// Joint kernel: per block (t-chunk 64, u-tile 16, b). 4 waves, wave = 16 t's.
// A-rows = 16 u's, K = H = 320 (10 steps of 32), 3 N-tiles of 16 (C padded 48).
// out_w fragments held in registers (30 x f16x8 = 120 VGPR), g-tile in LDS.
// ---------------------------------------------------------------------------
__global__ __launch_bounds__(256, 2)
void joint_kernel(const _Float16* __restrict__ F, const _Float16* __restrict__ G,
                  const _Float16* __restrict__ OWB, const float* __restrict__ out_b,
                  float* __restrict__ out) {
    __shared__ _Float16 glds[16 * 328];  // stride 328: balanced banks for b128

    const int tid = threadIdx.x;
    const int l   = tid & 63;
    const int w   = tid >> 6;
    const int q   = l >> 4;    // 0..3
    const int r16 = l & 15;
    const int tc  = blockIdx.x;  // 0..7 (t-chunk of 64)
    const int ut  = blockIdx.y;  // 0..7 (u-tile of 16)
    const int b   = blockIdx.z;  // 0..7
    const int u0  = ut * 16;

    // stage g-tile [16][320] -> LDS
    {
        const _Float16* gsrc = G + ((size_t)b * U_ + u0) * H_;
        for (int i = tid; i < 16 * 40; i += 256) {  // 40 x 16B per row
            int row = i / 40;
            int c8  = (i - row * 40) * 8;
            *(i32x4*)&glds[row * 328 + c8] = *(const i32x4*)(gsrc + row * H_ + c8);
        }
    }

    // out_w fragments (loop-invariant) + bias
    f16x8 bfr[3][10];
    float ob[3];
#pragma unroll
    for (int nt = 0; nt < 3; ++nt) {
        const int n = nt * 16 + r16;  // row of OWB (N=K-layout: [48][320])
#pragma unroll
        for (int s = 0; s < 10; ++s)
            bfr[nt][s] = *(const f16x8*)(OWB + (size_t)n * H_ + s * 32 + q * 8);
        ob[nt] = (n < C_) ? out_b[n] : 0.f;
    }

    __syncthreads();

    const int tbase = tc * 64 + w * 16;
    for (int tt = 0; tt < 16; ++tt) {
        const int t = tbase + tt;
        const _Float16* frow = F + ((size_t)b * T_ + t) * H_;

        f32x4 acc0 = {}, acc1 = {}, acc2 = {};
#pragma unroll
        for (int s = 0; s < 10; ++s) {
            f16x8 fv = *(const f16x8*)(frow + s * 32 + q * 8);         // broadcast (16 lanes/addr)
            f16x8 gv = *(const f16x8*)&glds[r16 * 328 + s * 32 + q * 8];
            f16x8 jv = fv + gv;                    // 4x v_pk_add_f16
            const f16x8 fz = {};
            jv = __builtin_elementwise_max(jv, fz); // 4x v_pk_max_f16 (relu)
            acc0 = __builtin_amdgcn_mfma_f32_16x16x32_f16(jv, bfr[0][s], acc0, 0, 0, 0);
            acc1 = __builtin_amdgcn_mfma_f32_16x16x32_f16(jv, bfr[1][s], acc1, 0, 0, 0);
            acc2 = __builtin_amdgcn_mfma_f32_16x16x32_f16(jv, bfr[2][s], acc2, 0, 0, 0);
        }

        // store: row = u-offset (q*4+rr), col = class (nt*16 + r16)
        float* orow = out + (((size_t)b * T_ + t) * U_ + u0) * C_;
#pragma unroll
        for (int rr = 0; rr < 4; ++rr) {
            const int m = q * 4 + rr;
            orow[m * C_ + r16]      = acc0[rr] + ob[0];
            orow[m * C_ + 16 + r16] = acc1[rr] + ob[1];
            if (r16 < 2)
                orow[m * C_ + 32 + r16] = acc2[rr] + ob[2];
        }
    }
}

// ---------------------------------------------------------------------------
extern "C" void kernel_launch(void* const* d_in, const int* in_sizes, int n_in,
                              void* d_out, int out_size, void* d_ws, size_t ws_size,
                              hipStream_t stream) {
    const float* enc_out  = (const float*)d_in[0];
    const float* pred_out = (const float*)d_in[1];
    const float* enc_w    = (const float*)d_in[2];
    const float* enc_b    = (const float*)d_in[3];
    const float* pred_w   = (const float*)d_in[4];
    const float* pred_b   = (const float*)d_in[5];
    const float* out_w    = (const float*)d_in[6];
    const float* out_b    = (const float*)d_in[7];
    float* out = (float*)d_out;

    char* ws = (char*)d_ws;
    _Float16* F   = (_Float16*)ws;                                    // 4096*320 fp16
    _Float16* G   = (_Float16*)(ws + (size_t)4096 * 320 * 2);         // 1024*320 fp16
    _Float16* OWB = (_Float16*)(ws + (size_t)4096 * 320 * 2 + (size_t)1024 * 320 * 2);  // 48*320 fp16

    prep_owb<<<60, 256, 0, stream>>>(out_w, OWB);
    proj_kernel<<<dim3(64, 5), 256, 0, stream>>>(enc_out, enc_w, enc_b, F, 768);
    proj_kernel<<<dim3(16, 5), 256, 0, stream>>>(pred_out, pred_w, pred_b, G, 320);
    joint_kernel<<<dim3(8, 8, 8), 256, 0, stream>>>(F, G, OWB, out_b, out);
}

// Round 3
// 51.124 us; speedup vs baseline: 1.2483x; 1.2483x over previous
//
#include <hip/hip_runtime.h>
#include <hip/hip_bf16.h>
#include <hip/hip_fp16.h>

// RNNT Joint: logits[b,t,u,c] = relu(f[b,t,:] + g[b,u,:]) . out_w[c,:] + out_b[c]
// f = enc_out @ enc_w^T + enc_b    [8,512,320]
// g = pred_out @ pred_w^T + pred_b [8,128,320]
// Sizes: B=8 T=512 U=128 E=768 P=320 H=320 C=34

typedef _Float16 f16x8 __attribute__((ext_vector_type(8)));
typedef __fp16   fp16x2 __attribute__((ext_vector_type(2)));
typedef float    f32x4 __attribute__((ext_vector_type(4)));
typedef int      i32x4 __attribute__((ext_vector_type(4)));

#define B_ 8
#define T_ 512
#define U_ 128
#define H_ 320
#define C_ 34

__device__ inline f16x8 pack8(f32x4 a, f32x4 b) {
    union { fp16x2 h[4]; f16x8 v; } u;
    u.h[0] = __builtin_amdgcn_cvt_pkrtz(a[0], a[1]);
    u.h[1] = __builtin_amdgcn_cvt_pkrtz(a[2], a[3]);
    u.h[2] = __builtin_amdgcn_cvt_pkrtz(b[0], b[1]);
    u.h[3] = __builtin_amdgcn_cvt_pkrtz(b[2], b[3]);
    return u.v;
}

// ---------------------------------------------------------------------------
// Fused projection GEMMs: Out[M][320] = A[M][K] * W[320][K]^T + bias, fp16 out.
// Blocks 0..319: enc (M=4096,K=768). Blocks 320..399: pred (M=1024,K=320).
// Tile 64x64, K-step 32, 4 waves (2x2 of 32x32), double-buffered LDS,
// register prefetch one K-step ahead -> ONE barrier per K-step.
// ---------------------------------------------------------------------------
__global__ __launch_bounds__(256, 4)
void proj_fused(const float* __restrict__ enc_out, const float* __restrict__ enc_w,
                const float* __restrict__ enc_b, const float* __restrict__ pred_out,
                const float* __restrict__ pred_w, const float* __restrict__ pred_b,
                _Float16* __restrict__ F, _Float16* __restrict__ G) {
    __shared__ _Float16 As[2][64 * 40];
    __shared__ _Float16 Ws[2][64 * 40];

    int blk = blockIdx.x;
    const float *A, *W, *bias;
    _Float16* Out;
    int K, mt, nt;
    if (blk < 320) {
        A = enc_out; W = enc_w; bias = enc_b; Out = F; K = 768;
        mt = blk & 63; nt = blk >> 6;
    } else {
        blk -= 320;
        A = pred_out; W = pred_w; bias = pred_b; Out = G; K = 320;
        mt = blk & 15; nt = blk >> 4;
    }
    const int bm = mt * 64;
    const int bn = nt * 64;

    const int tid = threadIdx.x;
    const int l   = tid & 63;
    const int w   = tid >> 6;
    const int wm  = (w >> 1) * 32;
    const int wn  = (w & 1) * 32;
    const int q   = l >> 4;      // 0..3 (k-slice group)
    const int r16 = l & 15;

    const int srow = tid >> 2;        // 0..63
    const int scol = (tid & 3) * 8;   // 0,8,16,24

    f32x4 acc[2][2] = {};

    const float* arow = A + (size_t)(bm + srow) * K + scol;
    const float* wrow = W + (size_t)(bn + srow) * K + scol;

    // prologue: prefetch K-step 0
    f32x4 a0 = *(const f32x4*)(arow);
    f32x4 a1 = *(const f32x4*)(arow + 4);
    f32x4 w0 = *(const f32x4*)(wrow);
    f32x4 w1 = *(const f32x4*)(wrow + 4);

    int p = 0;
    for (int k0 = 0; k0 < K; k0 += 32) {
        // pack + write LDS buf p
        *(f16x8*)&As[p][srow * 40 + scol] = pack8(a0, a1);
        *(f16x8*)&Ws[p][srow * 40 + scol] = pack8(w0, w1);

        // issue next K-step's global loads (latency hides under MFMA phase)
        if (k0 + 32 < K) {
            a0 = *(const f32x4*)(arow + k0 + 32);
            a1 = *(const f32x4*)(arow + k0 + 36);
            w0 = *(const f32x4*)(wrow + k0 + 32);
            w1 = *(const f32x4*)(wrow + k0 + 36);
        }

        __syncthreads();

        f16x8 afr0 = *(const f16x8*)&As[p][(wm + r16) * 40 + q * 8];
        f16x8 afr1 = *(const f16x8*)&As[p][(wm + 16 + r16) * 40 + q * 8];
        f16x8 bfr0 = *(const f16x8*)&Ws[p][(wn + r16) * 40 + q * 8];
        f16x8 bfr1 = *(const f16x8*)&Ws[p][(wn + 16 + r16) * 40 + q * 8];

        acc[0][0] = __builtin_amdgcn_mfma_f32_16x16x32_f16(afr0, bfr0, acc[0][0], 0, 0, 0);
        acc[0][1] = __builtin_amdgcn_mfma_f32_16x16x32_f16(afr0, bfr1, acc[0][1], 0, 0, 0);
        acc[1][0] = __builtin_amdgcn_mfma_f32_16x16x32_f16(afr1, bfr0, acc[1][0], 0, 0, 0);
        acc[1][1] = __builtin_amdgcn_mfma_f32_16x16x32_f16(afr1, bfr1, acc[1][1], 0, 0, 0);
        p ^= 1;
    }

    // Epilogue: C/D layout col = l&15, row = (l>>4)*4 + rr  [m89]
#pragma unroll
    for (int mrep = 0; mrep < 2; ++mrep) {
#pragma unroll
        for (int nrep = 0; nrep < 2; ++nrep) {
            int col  = bn + wn + nrep * 16 + r16;
            float bv = bias[col];
#pragma unroll
            for (int rr = 0; rr < 4; ++rr) {
                int row = bm + wm + mrep * 16 + q * 4 + rr;
                Out[(size_t)row * H_ + col] = (_Float16)(acc[mrep][nrep][rr] + bv);
            }
        }
    }
}

// ---------------------------------------------------------------------------
// Joint kernel: per block (t-chunk 64, u-tile 16, b). 4 waves, wave = 16 t's.
// A-rows = 16 u's, K = H = 320 (10 steps of 32), 3 N-tiles of 16 (C padded 48).
// out_w converted fp32->fp16 in-kernel, held in registers; g-tile in LDS.
// ---------------------------------------------------------------------------
__global__ __launch_bounds__(256, 2)
void joint_kernel(const _Float16* __restrict__ F, const _Float16* __restrict__ G,
                  const float* __restrict__ out_w, const float* __restrict__ out_b,
                  float* __restrict__ out) {
    __shared__ _Float16 glds[16 * 328];  // stride 328: balanced banks for b128

    const int tid = threadIdx.x;
    const int l   = tid & 63;
    const int w   = tid >> 6;
    const int q   = l >> 4;    // 0..3
    const int r16 = l & 15;
    const int tc  = blockIdx.x;  // 0..7 (t-chunk of 64)
    const int ut  = blockIdx.y;  // 0..7 (u-tile of 16)
    const int b   = blockIdx.z;  // 0..7
    const int u0  = ut * 16;

    // stage g-tile [16][320] -> LDS
    {
        const _Float16* gsrc = G + ((size_t)b * U_ + u0) * H_;
        for (int i = tid; i < 16 * 40; i += 256) {  // 40 x 16B per row
            int row = i / 40;
            int c8  = (i - row * 40) * 8;
            *(i32x4*)&glds[row * 328 + c8] = *(const i32x4*)(gsrc + row * H_ + c8);
        }
    }

    // out_w fragments (loop-invariant), converted fp32->fp16 here; + bias
    f16x8 bfr[3][10];
    float ob[3];
#pragma unroll
    for (int nt = 0; nt < 3; ++nt) {
        const int n = nt * 16 + r16;  // class row (N=K-layout: [34 valid][320])
        const bool valid = (n < C_);
        const float* wr = out_w + (size_t)n * H_;
        ob[nt] = valid ? out_b[n] : 0.f;
#pragma unroll
        for (int s = 0; s < 10; ++s) {
            f16x8 v = {};
            if (valid) {
                f32x4 x0 = *(const f32x4*)(wr + s * 32 + q * 8);
                f32x4 x1 = *(const f32x4*)(wr + s * 32 + q * 8 + 4);
                v = pack8(x0, x1);
            }
            bfr[nt][s] = v;
        }
    }

    __syncthreads();

    const int tbase = tc * 64 + w * 16;
    for (int tt = 0; tt < 16; ++tt) {
        const int t = tbase + tt;
        const _Float16* frow = F + ((size_t)b * T_ + t) * H_;

        f32x4 acc0 = {}, acc1 = {}, acc2 = {};
#pragma unroll
        for (int s = 0; s < 10; ++s) {
            f16x8 fv = *(const f16x8*)(frow + s * 32 + q * 8);  // broadcast (16 lanes/addr)
            f16x8 gv = *(const f16x8*)&glds[r16 * 328 + s * 32 + q * 8];
            f16x8 jv = fv + gv;                     // 4x v_pk_add_f16
            const f16x8 fz = {};
            jv = __builtin_elementwise_max(jv, fz); // 4x v_pk_max_f16 (relu)
            acc0 = __builtin_amdgcn_mfma_f32_16x16x32_f16(jv, bfr[0][s], acc0, 0, 0, 0);
            acc1 = __builtin_amdgcn_mfma_f32_16x16x32_f16(jv, bfr[1][s], acc1, 0, 0, 0);
            acc2 = __builtin_amdgcn_mfma_f32_16x16x32_f16(jv, bfr[2][s], acc2, 0, 0, 0);
        }

        // store: row (u-offset) = q*4+rr, col (class) = nt*16 + r16
        float* orow = out + (((size_t)b * T_ + t) * U_ + u0) * C_;
#pragma unroll
        for (int rr = 0; rr < 4; ++rr) {
            const int m = q * 4 + rr;
            orow[m * C_ + r16]      = acc0[rr] + ob[0];
            orow[m * C_ + 16 + r16] = acc1[rr] + ob[1];
            if (r16 < 2)
                orow[m * C_ + 32 + r16] = acc2[rr] + ob[2];
        }
    }
}

// ---------------------------------------------------------------------------
extern "C" void kernel_launch(void* const* d_in, const int* in_sizes, int n_in,
                              void* d_out, int out_size, void* d_ws, size_t ws_size,
                              hipStream_t stream) {
    const float* enc_out  = (const float*)d_in[0];
    const float* pred_out = (const float*)d_in[1];
    const float* enc_w    = (const float*)d_in[2];
    const float* enc_b    = (const float*)d_in[3];
    const float* pred_w   = (const float*)d_in[4];
    const float* pred_b   = (const float*)d_in[5];
    const float* out_w    = (const float*)d_in[6];
    const float* out_b    = (const float*)d_in[7];
    float* out = (float*)d_out;

    char* ws = (char*)d_ws;
    _Float16* F = (_Float16*)ws;                            // 4096*320 fp16
    _Float16* G = (_Float16*)(ws + (size_t)4096 * 320 * 2); // 1024*320 fp16

    proj_fused<<<400, 256, 0, stream>>>(enc_out, enc_w, enc_b,
                                        pred_out, pred_w, pred_b, F, G);
    joint_kernel<<<dim3(8, 8, 8), 256, 0, stream>>>(F, G, out_w, out_b, out);
}